// Round 3
// baseline (100.647 us; speedup 1.0000x reference)
//
#include <hip/hip_runtime.h>
#include <math.h>

#define C_IN  128
#define H_IN  56
#define W_IN  56
#define HW_IN (H_IN * W_IN)          // 3136
#define N_IN  8
#define O_MID 64

// Weff layout (floats): rows of 52 per channel, slot = (di*5+dj)*2 + k
// (50 used, 2 pad so rows are 16B-aligned for b128 LDS reads)
#define WROW     52
#define WEFF_FL  (C_IN * WROW)        // 6656
#define BEFF_OFF WEFF_FL

// fused tile geometry: 8x8 output tile, 12x12 halo (56 = 7*8, no partial tiles)
#define TS    8
#define HS    12
#define HPX   144                     // 12*12 halo px = 9 * 16 (zero idle lanes)

// Module-scope weff buffer (d_ws unused: R2 proved the 256 MiB harness poison
// fill runs regardless, so ws buys nothing; module global is simpler).
__device__ __align__(16) float g_weff[WEFF_FL + 4];

// ---------------- k_weff: coalesced fold of O=64 ----------------
// R3 change: FULL unroll of the o-loop -> 64 independent loads in flight,
// one vmcnt wait instead of 8 serialized ~900cy waits (unroll-8 before).
__global__ __launch_bounds__(256) void k_weff(const float* __restrict__ Wt,
                                              const float* __restrict__ bias,
                                              const float* __restrict__ Wlin,
                                              const float* __restrict__ blin) {
    const int t = threadIdx.x;
    const int e = blockIdx.x * 256 + t;

    if (e < 3200) {
        float a0 = 0.f, a1 = 0.f;
#pragma unroll
        for (int o = 0; o < O_MID; ++o) {
            const float wt = Wt[o * 3200 + e];
            a0 = fmaf(Wlin[o], wt, a0);
            a1 = fmaf(Wlin[64 + o], wt, a1);
        }
        const int c = e / 25;
        const int p = e - c * 25;
        g_weff[c * WROW + p * 2 + 0] = a0;
        g_weff[c * WROW + p * 2 + 1] = a1;
    }

    if (blockIdx.x == 12 && t >= 128 && t < 192) {
        const int o = t - 128;
        float v0 = Wlin[o] * bias[o];
        float v1 = Wlin[64 + o] * bias[o];
#pragma unroll
        for (int off = 32; off; off >>= 1) {
            v0 += __shfl_down(v0, off, 64);
            v1 += __shfl_down(v1, off, 64);
        }
        if (o == 0) {
            g_weff[BEFF_OFF + 0] = v0 + blin[0];
            g_weff[BEFF_OFF + 1] = v1 + blin[1];
        }
    }
}

// ---------------- k_fused: halo GEMM into LDS + final stats, one pass ----------
// R1's fusion (no G round-trip, no extra dispatch) + R2's prefetch ILP (the fix
// for R1's serialized-load latency disease).
// grid (n=8, tile=49): linear id = n + 8*tile -> id%8 = n -> all blocks of
// batch n on one XCD; x[n] (1.6 MB) L2-resident so halo re-reads are cheap.
// Phase B: 9 wave-passes of 16 px x 4-way c-split cover 144 halo px exactly;
// per pass ALL 32 x-loads issued before the FMA loop (one latency, not 32).
// G-in-LDS layout [p][hp][k]: phase-B stores = 16-lane contiguous 128B runs;
// phase-C reads spread over all 32 banks (<=2-way).
__global__ __launch_bounds__(256) void k_fused(const float* __restrict__ x,
                                               float* __restrict__ out) {
    __shared__ float wls[WEFF_FL + 4];    // 26640 B: Weff rows + beff
    __shared__ float gls[25 * HPX * 2];   // 28800 B: [p][hp][k]

    const int tid = threadIdx.x;
#pragma unroll
    for (int r = 0; r < 7; ++r) {
        const int i4 = tid + 256 * r;
        if (i4 < 1665)
            *(float4*)&wls[i4 * 4] = *(const float4*)&g_weff[i4 * 4];
    }
    __syncthreads();

    const int n   = blockIdx.x;
    const int bx  = blockIdx.y;
    const int ty8 = bx / 7;
    const int tx8 = bx - ty8 * 7;
    const int y0  = ty8 * TS - 2;         // halo origin (may be -2)
    const int x0  = tx8 * TS - 2;

    const int wv   = tid >> 6;
    const int lane = tid & 63;
    const int cgrp = lane >> 4;
    const int pxi  = lane & 15;

    const float* xn = x + (size_t)n * (C_IN * HW_IN);

#pragma unroll
    for (int ps = 0; ps < 3; ++ps) {
        const int base = ps * 64 + wv * 16;   // wave-uniform
        if (base < HPX) {
            const int hp = base + pxi;        // < 144 always (144 = 9*16)
            const int hy = hp / HS;
            const int hx = hp - hy * HS;
            const int gy = y0 + hy;
            const int gx = x0 + hx;
            const bool in = ((unsigned)gy < H_IN) && ((unsigned)gx < W_IN);
            const float* xc = xn + (in ? (gy * W_IN + gx) : 0);

            // prefetch: 32 independent loads in flight (R2's ILP fix)
            float xv[32];
#pragma unroll
            for (int s = 0; s < 32; ++s)
                xv[s] = xc[(size_t)(s * 4 + cgrp) * HW_IN];
#pragma unroll
            for (int s = 0; s < 32; ++s)
                xv[s] = in ? xv[s] : 0.f;     // zero-pad outside image

            float acc[50];
#pragma unroll
            for (int i = 0; i < 50; ++i) acc[i] = 0.f;

#pragma unroll
            for (int s = 0; s < 32; ++s) {
                const float* wr = &wls[(s * 4 + cgrp) * WROW];
#pragma unroll
                for (int i = 0; i < 50; ++i)
                    acc[i] = fmaf(xv[s], wr[i], acc[i]);
            }

            // reduce across cgrp (lane bits 4,5)
#pragma unroll
            for (int i = 0; i < 50; ++i) {
                float v = acc[i];
                v += __shfl_xor(v, 16, 64);
                v += __shfl_xor(v, 32, 64);
                acc[i] = v;
            }

            if (cgrp == 0) {
#pragma unroll
                for (int p = 0; p < 25; ++p)
                    *(float2*)&gls[(p * HPX + hp) * 2] =
                        make_float2(acc[p * 2], acc[p * 2 + 1]);
            }
        }
    }
    __syncthreads();

    // ---- phase C: per-(px,k) stats from LDS, write output ----
    if (tid < 128) {
        const int px = tid >> 1;
        const int k  = tid & 1;
        const int ty = px >> 3;
        const int tx = px & 7;
        const float be = wls[BEFF_OFF + k];

        float A = 0.f, X = 0.f, Y = 0.f, Cs = 0.f;
#pragma unroll
        for (int di = 0; di < 5; ++di) {
#pragma unroll
            for (int dj = 0; dj < 5; ++dj) {
                const int p  = di * 5 + dj;
                const int hp = (ty + di) * HS + (tx + dj);
                const float v = gls[(p * HPX + hp) * 2 + k] + be;
                const float a = fabsf(v);
                A += a;
                X  = fmaf(a, (float)(dj - 2), X);
                Y  = fmaf(a, (float)(di - 2), Y);
                Cs += v;
            }
        }
        const float xd = X / A, yd = Y / A;
        const float o  = Cs * expf(-0.5f * sqrtf(xd * xd + yd * yd));
        const int hw   = (ty8 * TS + ty) * W_IN + (tx8 * TS + tx);
        out[((size_t)n * HW_IN + hw) * 2 + k] = o;
    }
}

extern "C" void kernel_launch(void* const* d_in, const int* in_sizes, int n_in,
                              void* d_out, int out_size, void* d_ws, size_t ws_size,
                              hipStream_t stream) {
    const float* x    = (const float*)d_in[0];
    const float* Wt   = (const float*)d_in[1];
    const float* bias = (const float*)d_in[2];
    const float* Wlin = (const float*)d_in[3];
    const float* blin = (const float*)d_in[4];
    (void)d_ws; (void)ws_size;

    k_weff<<<dim3(13), dim3(256), 0, stream>>>(Wt, bias, Wlin, blin);
    k_fused<<<dim3(N_IN, 49), dim3(256), 0, stream>>>(x, (float*)d_out);
}